// Round 1
// baseline (641.279 us; speedup 1.0000x reference)
//
#include <hip/hip_runtime.h>

#define BB 4096
#define NN 32768
#define LL 12
#define KK 64

// One wave (64 lanes) per (b,l) task. Total tasks = B*L = 49152.
// 12288 blocks x 256 threads (4 waves) = 49152 waves -> 1 task/wave.
constexpr int WAVES_PER_BLOCK = 4;
constexpr int NBLOCKS = (BB * LL) / WAVES_PER_BLOCK;  // 12288

__global__ __launch_bounds__(256) void hsm_partial(
    const float* __restrict__ x,
    const int* __restrict__ brother,
    const int* __restrict__ p_y,
    float* __restrict__ partials) {

    const int wave_in_block = threadIdx.x >> 6;
    const int lane = threadIdx.x & 63;
    const int waves_total = gridDim.x * WAVES_PER_BLOCK;
    const int wave_id = blockIdx.x * WAVES_PER_BLOCK + wave_in_block;
    const int total = BB * LL;

    float local = 0.f;
    for (int t = wave_id; t < total; t += waves_total) {
        const int b = t / LL;
        const int l = t - b * LL;
        const int idx = brother[l * KK + lane];
        const float v = x[(size_t)b * NN + idx];

        // label = first lane where brother[l,k] == p_y[l]  (argmax of bool)
        const unsigned long long m = __ballot(idx == p_y[l]);
        const int label = __ffsll(m) - 1;

        // wave-wide max
        float mx = v;
        #pragma unroll
        for (int o = 32; o > 0; o >>= 1) mx = fmaxf(mx, __shfl_xor(mx, o));
        // wave-wide sum of exp(v - mx)
        float s = __expf(v - mx);
        #pragma unroll
        for (int o = 32; o > 0; o >>= 1) s += __shfl_xor(s, o);
        const float lse = mx + __logf(s);

        const float vsel = __shfl(v, label);
        local += (lse - vsel);  // = -logp[b,l,label]
    }

    __shared__ float red[WAVES_PER_BLOCK];
    if (lane == 0) red[wave_in_block] = local;
    __syncthreads();
    if (threadIdx.x == 0) {
        float s = 0.f;
        #pragma unroll
        for (int i = 0; i < WAVES_PER_BLOCK; ++i) s += red[i];
        partials[blockIdx.x] = s;  // every block writes -> no 0xAA poison issue
    }
}

__global__ __launch_bounds__(256) void hsm_final(
    const float* __restrict__ partials, float* __restrict__ out, int n) {
    float s = 0.f;
    for (int i = threadIdx.x; i < n; i += 256) s += partials[i];
    #pragma unroll
    for (int o = 32; o > 0; o >>= 1) s += __shfl_xor(s, o);
    __shared__ float red[4];
    const int wave = threadIdx.x >> 6, lane = threadIdx.x & 63;
    if (lane == 0) red[wave] = s;
    __syncthreads();
    if (threadIdx.x == 0) {
        out[0] = (red[0] + red[1] + red[2] + red[3]) / (float)BB;
    }
}

extern "C" void kernel_launch(void* const* d_in, const int* in_sizes, int n_in,
                              void* d_out, int out_size, void* d_ws, size_t ws_size,
                              hipStream_t stream) {
    const float* x       = (const float*)d_in[0];
    const int*   brother = (const int*)d_in[1];
    const int*   p_y     = (const int*)d_in[2];
    // d_in[3] = y : unused by the reference
    float* out      = (float*)d_out;
    float* partials = (float*)d_ws;  // NBLOCKS floats = 48 KB << ws_size

    hsm_partial<<<NBLOCKS, 256, 0, stream>>>(x, brother, p_y, partials);
    hsm_final<<<1, 256, 0, stream>>>(partials, out, NBLOCKS);
}

// Round 2
// 636.572 us; speedup vs baseline: 1.0074x; 1.0074x over previous
//
#include <hip/hip_runtime.h>

#define BB 4096
#define NN 32768
#define LL 12
#define KK 64

// Each wave owns one l (of 12) and a CHUNK of rows b. brother[l,:] and the
// label lane are hoisted out of the b-loop (they depend only on l). All CHUNK
// scattered row-gathers are issued before the reductions -> ~CHUNK*62 cache
// lines in flight per wave instead of 62 per wave-lifetime (R0 was
// latency-bound: 1 gather per wave, ~0.5 TB/s effective).
constexpr int CHUNK = 8;                        // rows per wave
constexpr int NWAVES = LL * (BB / CHUNK);       // 6144 waves = 24/CU
constexpr int WPB = 4;                          // waves per block
constexpr int NBLOCKS = NWAVES / WPB;           // 1536

__global__ __launch_bounds__(256) void hsm_partial(
    const float* __restrict__ x,
    const int* __restrict__ brother,
    const int* __restrict__ p_y,
    float* __restrict__ partials) {

    const int wave_in_block = threadIdx.x >> 6;
    const int lane = threadIdx.x & 63;
    const int wid = blockIdx.x * WPB + wave_in_block;

    // wid = chunk*12 + l : consecutive waves share the same rows (L2 line
    // sharing across the 12 l's: 768 cols/row -> ~540 lines vs 744 unshared)
    const int chunk = wid / LL;
    const int l = wid - chunk * LL;
    const int b0 = chunk * CHUNK;

    // hoisted per-l state
    const int col = brother[l * KK + lane];
    const int py = p_y[l];
    const int label = __ffsll(__ballot(col == py)) - 1;

    const float* __restrict__ xp = x + (size_t)b0 * NN + col;

    // issue all gathers first (independent -> all in flight)
    float v[CHUNK];
    #pragma unroll
    for (int bi = 0; bi < CHUNK; ++bi)
        v[bi] = xp[(size_t)bi * NN];

    // CHUNK independent reduction chains -> shuffle latency hidden by ILP
    float local = 0.f;
    #pragma unroll
    for (int bi = 0; bi < CHUNK; ++bi) {
        float mx = v[bi];
        #pragma unroll
        for (int o = 32; o > 0; o >>= 1) mx = fmaxf(mx, __shfl_xor(mx, o));
        float s = __expf(v[bi] - mx);
        #pragma unroll
        for (int o = 32; o > 0; o >>= 1) s += __shfl_xor(s, o);
        const float lse = mx + __logf(s);
        local += lse - __shfl(v[bi], label);
    }

    __shared__ float red[WPB];
    if (lane == 0) red[wave_in_block] = local;
    __syncthreads();
    if (threadIdx.x == 0) {
        float s = 0.f;
        #pragma unroll
        for (int i = 0; i < WPB; ++i) s += red[i];
        partials[blockIdx.x] = s;   // every block writes -> no poison issue
    }
}

__global__ __launch_bounds__(256) void hsm_final(
    const float* __restrict__ partials, float* __restrict__ out, int n) {
    float s = 0.f;
    for (int i = threadIdx.x; i < n; i += 256) s += partials[i];
    #pragma unroll
    for (int o = 32; o > 0; o >>= 1) s += __shfl_xor(s, o);
    __shared__ float red[4];
    const int wave = threadIdx.x >> 6, lane = threadIdx.x & 63;
    if (lane == 0) red[wave] = s;
    __syncthreads();
    if (threadIdx.x == 0) {
        out[0] = (red[0] + red[1] + red[2] + red[3]) / (float)BB;
    }
}

extern "C" void kernel_launch(void* const* d_in, const int* in_sizes, int n_in,
                              void* d_out, int out_size, void* d_ws, size_t ws_size,
                              hipStream_t stream) {
    const float* x       = (const float*)d_in[0];
    const int*   brother = (const int*)d_in[1];
    const int*   p_y     = (const int*)d_in[2];
    // d_in[3] = y : unused by the reference
    float* out      = (float*)d_out;
    float* partials = (float*)d_ws;  // NBLOCKS floats = 6 KB << ws_size

    hsm_partial<<<NBLOCKS, 256, 0, stream>>>(x, brother, p_y, partials);
    hsm_final<<<1, 256, 0, stream>>>(partials, out, NBLOCKS);
}